// Round 11
// baseline (523.309 us; speedup 1.0000x reference)
//
#include <hip/hip_runtime.h>
#include <hip/hip_fp16.h>

// RelMultiHeadAttention (Transformer-XL) on gfx950.
// B=2, S=2048, D=1024, H=16, hd=64.
// R17: fused_k FROZEN at R16 (291us champion/control). Fixes the two
// non-fused issues: (1) bf16-input fast path now actually engages — qinb
// lives in the attnb slot (written only by fused_k, later) so job 0 is
// bf16 ALWAYS; kvinb gated at ws>=63MB (was 76) for jobs 1/2; pos stays
// f32. (2) gemm_o retiled 128x128 -> 64x128: 512 blocks = 2/CU, 8 waves/CU
// (was 1 block/CU = 12% occupancy, pure latency exposure). Same MFMA order
// => bit-identical output.

typedef float  floatx4 __attribute__((ext_vector_type(4)));
typedef __bf16 bf16x8  __attribute__((ext_vector_type(8)));
typedef _Float16 f16x8 __attribute__((ext_vector_type(8)));
typedef _Float16 f16x4 __attribute__((ext_vector_type(4)));
typedef _Float16 f16x2 __attribute__((ext_vector_type(2)));

#define LSTR 40   // proj-GEMM LDS row stride (bf16)
#define SCL 0.18033688f   // 0.125 * log2(e): score scale with exp->exp2 fold

struct GP {
  const void* A;
  const __bf16* B;
  int lda, ldb, K;
  float* outF;
  __bf16* out1;
  const float* bias;
};

// Output projection (attn bf16 @ Wo + bo -> f32), 64x128 tiles, 512 blocks.
__global__ void __launch_bounds__(256) gemm_o(GP p) {
  __shared__ __align__(16) __bf16 lA[64 * 32];
  __shared__ __align__(16) __bf16 lB[128 * 32];
  const int t = threadIdx.x;
  const int wave = t >> 6, lane = t & 63;
  const int m0 = blockIdx.y * 64, n0 = blockIdx.x * 128;
  const __bf16* Ab = (const __bf16*)p.A;
  const __bf16* Bb = p.B;

  floatx4 acc[2][4];
#pragma unroll
  for (int i = 0; i < 2; i++)
#pragma unroll
    for (int j = 0; j < 4; j++) acc[i][j] = floatx4{0.f, 0.f, 0.f, 0.f};

  const int lr = lane & 15, lq = lane >> 4;
  const int wr = (wave >> 1) << 5, wc = (wave & 1) << 6;

  for (int kk = 0; kk < 1024; kk += 32) {
    {
      const int row = t >> 2, ch = (t & 3) << 3;   // 64 rows x 4 chunks
      *(bf16x8*)&lA[row * 32 + ch] = *(const bf16x8*)(Ab + (long)(m0 + row) * 1024 + kk + ch);
    }
#pragma unroll
    for (int i = 0; i < 2; i++) {
      const int idx = (i << 8) + t;                // 0..511 -> 128 rows
      const int row = idx >> 2, ch = (idx & 3) << 3;
      *(bf16x8*)&lB[row * 32 + ch] = *(const bf16x8*)(Bb + (long)(n0 + row) * 1024 + kk + ch);
    }
    __syncthreads();
    bf16x8 aF[2], bF[4];
#pragma unroll
    for (int i = 0; i < 2; i++)
      aF[i] = *(bf16x8*)&lA[(wr + i * 16 + lr) * 32 + (lq << 3)];
#pragma unroll
    for (int j = 0; j < 4; j++)
      bF[j] = *(bf16x8*)&lB[(wc + j * 16 + lr) * 32 + (lq << 3)];
#pragma unroll
    for (int i = 0; i < 2; i++)
#pragma unroll
      for (int j = 0; j < 4; j++)
        acc[i][j] = __builtin_amdgcn_mfma_f32_16x16x32_bf16(aF[i], bF[j], acc[i][j], 0, 0, 0);
    __syncthreads();
  }
#pragma unroll
  for (int i = 0; i < 2; i++)
#pragma unroll
    for (int j = 0; j < 4; j++) {
      int col = n0 + wc + j * 16 + lr;
#pragma unroll
      for (int g = 0; g < 4; g++) {
        int rl = m0 + wr + i * 16 + (lq << 2) + g;
        p.outF[(long)rl * 1024 + col] = acc[i][j][g] + p.bias[col];
      }
    }
}

// ---- merged Q/K/V/R projection: one launch, job table ----------------------
struct QPAll {
  const float *qin, *kvin, *pos;
  const __bf16 *qinb, *kvinb;           // pre-converted bf16 (kvinb may be null)
  const __bf16 *Wtq, *Wtk, *Wtv, *Wtr;
  const float *bq, *bk, *bv, *rrb;
  __bf16 *qb, *qrr, *kb, *rb;
  _Float16 *vt;
};

__global__ void __launch_bounds__(256) qkvr_k(QPAll p) {
  __shared__ __align__(16) __bf16 lA[128 * LSTR];
  __shared__ __align__(16) __bf16 lB[128 * LSTR];
  const int jb = blockIdx.x;
  const int job = (jb >= 768) ? 3 : (jb >> 8);
  const int local = jb - ((job == 3) ? 768 : (job << 8));
  const int m0 = (local >> 3) * 128, n0 = (local & 7) * 128;

  const float* Af = nullptr; const __bf16* Ab = nullptr;
  const __bf16* B; const float* bias;
  if (job == 0)      { Ab = p.qinb;  B = p.Wtq; bias = p.bq; }
  else if (job == 1) { Ab = p.kvinb; Af = p.kvin; B = p.Wtk; bias = p.bk; }
  else if (job == 2) { Ab = p.kvinb; Af = p.kvin; B = p.Wtv; bias = p.bv; }
  else               { Af = p.pos;   B = p.Wtr; bias = nullptr; }
  const bool abf16 = (Ab != nullptr);

  const int t = threadIdx.x;
  const int wave = t >> 6, lane = t & 63;

  floatx4 acc[4][4];
#pragma unroll
  for (int i = 0; i < 4; i++)
#pragma unroll
    for (int j = 0; j < 4; j++) acc[i][j] = floatx4{0.f, 0.f, 0.f, 0.f};

  const int lr = lane & 15, lq = lane >> 4;
  const int wr = (wave >> 1) << 6, wc = (wave & 1) << 6;

  for (int kk = 0; kk < 1024; kk += 32) {
#pragma unroll
    for (int i = 0; i < 2; i++) {
      const int idx = (i << 8) + t;        // 0..511 -> 128 rows x 4 chunks
      const int row = idx >> 2, ch = (idx & 3) << 3;
      if (abf16) {
        *(bf16x8*)&lA[row * LSTR + ch] = *(const bf16x8*)(Ab + (long)(m0 + row) * 1024 + kk + ch);
      } else {
        const float* ap = Af + (long)(m0 + row) * 1024 + kk + ch;
        float4 f0 = *(const float4*)ap;
        float4 f1 = *(const float4*)(ap + 4);
        bf16x8 o;
        o[0] = (__bf16)f0.x; o[1] = (__bf16)f0.y; o[2] = (__bf16)f0.z; o[3] = (__bf16)f0.w;
        o[4] = (__bf16)f1.x; o[5] = (__bf16)f1.y; o[6] = (__bf16)f1.z; o[7] = (__bf16)f1.w;
        *(bf16x8*)&lA[row * LSTR + ch] = o;
      }
      *(bf16x8*)&lB[row * LSTR + ch] = *(const bf16x8*)(B + (long)(n0 + row) * 1024 + kk + ch);
    }
    __syncthreads();
    bf16x8 aF[4], bF[4];
#pragma unroll
    for (int i = 0; i < 4; i++)
      aF[i] = *(bf16x8*)&lA[(wr + i * 16 + lr) * LSTR + (lq << 3)];
#pragma unroll
    for (int i = 0; i < 4; i++)
      bF[i] = *(bf16x8*)&lB[(wc + i * 16 + lr) * LSTR + (lq << 3)];
#pragma unroll
    for (int i = 0; i < 4; i++)
#pragma unroll
      for (int j = 0; j < 4; j++)
        acc[i][j] = __builtin_amdgcn_mfma_f32_16x16x32_bf16(aF[i], bF[j], acc[i][j], 0, 0, 0);
    __syncthreads();
  }

  // epilogue per job; C/D: col=lane&15, row=(lane>>4)*4+reg
#pragma unroll
  for (int i = 0; i < 4; i++)
#pragma unroll
    for (int j = 0; j < 4; j++) {
      int col = n0 + wc + j * 16 + lr;
#pragma unroll
      for (int g = 0; g < 4; g++) {
        int rl = m0 + wr + i * 16 + (lq << 2) + g;
        float val = acc[i][j][g];
        int hh = col >> 6, d = col & 63;
        if (job == 3) {
          long dst = (((long)hh * 2048 + rl) << 6) + d;
          p.rb[dst] = (__bf16)val;
        } else {
          int bb = rl >> 11, s = rl & 2047;
          float v = val + bias[col];
          if (job == 0) {
            long dst = (((long)(bb * 16 + hh) * 2048 + s) << 6) + d;
            p.qb[dst] = (__bf16)v;
            p.qrr[dst] = (__bf16)(v + p.rrb[col]);
          } else if (job == 1) {
            long dst = (((long)(bb * 16 + hh) * 2048 + s) << 6) + d;
            p.kb[dst] = (__bf16)v;
          } else {
            long dst = ((((long)(bb * 16 + hh)) << 6) + d) * 2048 + s;
            p.vt[dst] = (_Float16)v;
          }
        }
      }
    }
}

// cb pre-scaled by 0.125*log2(e) so fused exp2 needs no extra factor.
__global__ void __launch_bounds__(256) cb_k(const __bf16* kb, const float* rwb, float* cb) {
  long id = (long)blockIdx.x * 256 + threadIdx.x;  // 32*2048
  int z = (int)(id >> 11);
  int j = (int)(id & 2047);
  int h = z & 15;
  const __bf16* kp = kb + (((long)z * 2048 + j) << 6);
  float s = 0.f;
#pragma unroll
  for (int c = 0; c < 8; c++) {
    bf16x8 kv = *(const bf16x8*)(kp + c * 8);
#pragma unroll
    for (int e = 0; e < 8; e++) s += rwb[h * 64 + c * 8 + e] * (float)kv[e];
  }
  cb[id] = s * SCL;
}

// Weight transposes (blocks 0..1279) + input f32->bf16 cvt jobs:
// blocks 1280..1535 = q (always), 1536..1791 = kv (only if big1 grid).
struct TRP {
  const float* src[5]; __bf16* dst[5];
  const float* csrc[2]; __bf16* cdst[2]; long clen[2];
};
__global__ void __launch_bounds__(256) tr_cvt_all(TRP p) {
  const int id = blockIdx.x;
  if (id >= 1280) {
    const int cj = (id - 1280) >> 8;
    const int cbk = (id - 1280) & 255;
    const float* s = p.csrc[cj];
    __bf16* d = p.cdst[cj];
    const long n = p.clen[cj];
    for (long i = ((long)cbk * 256 + threadIdx.x) * 8; i < n; i += (long)256 * 256 * 8) {
      float4 f0 = *(const float4*)(s + i);
      float4 f1 = *(const float4*)(s + i + 4);
      bf16x8 o;
      o[0] = (__bf16)f0.x; o[1] = (__bf16)f0.y; o[2] = (__bf16)f0.z; o[3] = (__bf16)f0.w;
      o[4] = (__bf16)f1.x; o[5] = (__bf16)f1.y; o[6] = (__bf16)f1.z; o[7] = (__bf16)f1.w;
      *(bf16x8*)(d + i) = o;
    }
    return;
  }
  __shared__ float tile[64][65];
  const int which = id >> 8;
  const int local = id & 255;
  const int bx = local & 15, by = local >> 4;
  const float* src = p.src[which];
  __bf16* dst = p.dst[which];
  int tx = threadIdx.x & 63, ty = threadIdx.x >> 6;
#pragma unroll
  for (int r = ty; r < 64; r += 4)
    tile[r][tx] = src[(long)(by * 64 + r) * 1024 + bx * 64 + tx];
  __syncthreads();
#pragma unroll
  for (int r = ty; r < 64; r += 4)
    dst[(long)(bx * 64 + r) * 1024 + by * 64 + tx] = (__bf16)tile[tx][r];
}

// -------- fused scores + rel-shift + softmax + PV (FROZEN from R14/R16) ----
#define QW 256
#define QSTR3 264                         // row stride f16 (256+8)
#define SM_ONE (32 * QSTR3 * 2)           // 16896 B per strip
#define FUSED_SMEM (2 * SM_ONE + 2048)    // 35840 B -> 4 blocks/CU

__global__ void __launch_bounds__(256, 4) fused_k(const __bf16* __restrict__ qb,
                                                  const __bf16* __restrict__ qrr,
                                                  const __bf16* __restrict__ kb,
                                                  const _Float16* __restrict__ vt,
                                                  const __bf16* __restrict__ rb,
                                                  const float* __restrict__ cb,
                                                  __bf16* __restrict__ attnb) {
  extern __shared__ char smem[];
  _Float16* qkS = (_Float16*)smem;              // [32][QSTR3]
  _Float16* xS  = (_Float16*)(smem + SM_ONE);   // [32][QSTR3]
  _Float16* xB  = (_Float16*)(smem + 2 * SM_ONE);  // [1024] boundary row
  __shared__ float sInv[32];

  const int t = threadIdx.x;
  const int w = t >> 6, lane = t & 63, lr = lane & 15, lq = lane >> 4;
  // XCD swizzle: all 64 tiles of a (b,h) on one XCD.
  const int obid = blockIdx.x;
  const int bid = ((obid & 7) << 8) | (obid >> 3);
  const int z  = bid >> 6;
  const int i0 = (bid & 63) << 5;
  const int b = z >> 4, h = z & 15;
  const bool early = (i0 <= 1023);
  const int astart = early ? i0 + 1 : i0;   // 32 MFMA x-rows [astart, astart+32)
  const int grow = early ? 0 : 31;          // boundary strip row
  const int c0   = early ? 0 : i0 + 33;     // boundary col range start

  // B-frags: q rows i0+rg*16+lr, qrr rows astart+rg*16+lr
  bf16x8 fq[2][2], fr[2][2];
#pragma unroll
  for (int rg2 = 0; rg2 < 2; rg2++) {
    const __bf16* qp = qb + (((long)z * 2048 + i0 + rg2 * 16 + lr) << 6) + lq * 8;
    fq[rg2][0] = *(const bf16x8*)qp; fq[rg2][1] = *(const bf16x8*)(qp + 32);
    const __bf16* rp = qrr + (((long)z * 2048 + astart + rg2 * 16 + lr) << 6) + lq * 8;
    fr[rg2][0] = *(const bf16x8*)rp; fr[rg2][1] = *(const bf16x8*)(rp + 32);
  }

  const __bf16* kbz = kb + (((long)z * 2048) << 6);
  const __bf16* rbh = rb + (((long)h * 2048) << 6);
  const float* cbz = cb + (long)z * 2048;
  const _Float16* vtz = vt + (((long)z) << 6) * 2048;

  // ---- boundary row, once per block, coalesced: 8 lanes per column --------
  {
    const int ga    = early ? i0 : i0 + 32;
    const int m0g   = early ? (2047 - i0) : 0;
    int ncols = early ? (i0 + 1) : (2015 - i0);
    if (ncols < 0) ncols = 0;
    const int dl = (t & 7) << 3;          // 8 d's per lane
    bf16x8 qv = *(const bf16x8*)(qrr + (((long)z * 2048 + ga) << 6) + dl);
    for (int c = t >> 3; c < ncols; c += 32) {
      bf16x8 rv = *(const bf16x8*)(rbh + ((long)(m0g + c) << 6) + dl);
      float s = 0.f;
#pragma unroll
      for (int e = 0; e < 8; e++) s += (float)qv[e] * (float)rv[e];
      s += __shfl_xor(s, 1, 64);
      s += __shfl_xor(s, 2, 64);
      s += __shfl_xor(s, 4, 64);
      if ((t & 7) == 0) xB[c] = (_Float16)(s * SCL);
    }
  }
  __syncthreads();   // xB visible to all waves

  const int erow = w * 8 + (lane >> 3);     // exp row for this lane
  const int ecol = (lane & 7) * 16;         // exp col base within half-pass
  const int rg = w >> 1, sl = w & 1;        // PV role: row-group, k-slice

  floatx4 oacc[4];
#pragma unroll
  for (int s = 0; s < 4; s++) oacc[s] = floatx4{0.f, 0.f, 0.f, 0.f};
  float psum = 0.f;

  for (int kp = 0; kp < 8; kp++) {
    const int J0 = kp << 8;

    // qk MFMA (+cb fold): 16 j-tiles, wave does 4. D: row=key-local, col=q-row.
#pragma unroll
    for (int s = 0; s < 4; s++) {
      const int jt = ((w << 2) + s) << 4;     // 0..240
      const __bf16* ap = kbz + ((long)(J0 + jt + lr) << 6) + lq * 8;
      bf16x8 a0 = *(const bf16x8*)ap, a1 = *(const bf16x8*)(ap + 32);
      floatx4 cbv = *(const floatx4*)(cbz + J0 + jt + lq * 4);
      floatx4 c0v{0.f, 0.f, 0.f, 0.f}, c1v{0.f, 0.f, 0.f, 0.f};
      c0v = __builtin_amdgcn_mfma_f32_16x16x32_bf16(a0, fq[0][0], c0v, 0, 0, 0);
      c0v = __builtin_amdgcn_mfma_f32_16x16x32_bf16(a1, fq[0][1], c0v, 0, 0, 0);
      c1v = __builtin_amdgcn_mfma_f32_16x16x32_bf16(a0, fq[1][0], c1v, 0, 0, 0);
      c1v = __builtin_amdgcn_mfma_f32_16x16x32_bf16(a1, fq[1][1], c1v, 0, 0, 0);
      f16x4 s0v, s1v;
#pragma unroll
      for (int g = 0; g < 4; g++) {
        s0v[g] = (_Float16)(c0v[g] * SCL + cbv[g]);
        s1v[g] = (_Float16)(c1v[g] * SCL + cbv[g]);
      }
      *(f16x4*)&qkS[lr * QSTR3 + jt + lq * 4] = s0v;
      *(f16x4*)&qkS[(16 + lr) * QSTR3 + jt + lq * 4] = s1v;
    }

    // x MFMA: m-window = 287 consecutive values -> <=19 tiles over 4 waves;
    // wave-uniform predicate. Scatter with shift pre-applied.
    const int mb = ((J0 - astart - 32) & 2047) & ~15;
#pragma unroll
    for (int s = 0; s < 5; s++) {
      const int mt = w + (s << 2);
      if (mt < 19) {
        const int m0 = (mb + (mt << 4)) & 2047;
        const __bf16* rp2 = rbh + ((long)(m0 + lr) << 6) + lq * 8;
        bf16x8 r0 = *(const bf16x8*)rp2, r1 = *(const bf16x8*)(rp2 + 32);
        floatx4 x0{0.f, 0.f, 0.f, 0.f}, x1{0.f, 0.f, 0.f, 0.f};
        x0 = __builtin_amdgcn_mfma_f32_16x16x32_bf16(r0, fr[0][0], x0, 0, 0, 0);
        x0 = __builtin_amdgcn_mfma_f32_16x16x32_bf16(r1, fr[0][1], x0, 0, 0, 0);
        x1 = __builtin_amdgcn_mfma_f32_16x16x32_bf16(r0, fr[1][0], x1, 0, 0, 0);
        x1 = __builtin_amdgcn_mfma_f32_16x16x32_bf16(r1, fr[1][1], x1, 0, 0, 0);
#pragma unroll
        for (int rg2 = 0; rg2 < 2; rg2++) {
          const int a = astart + (rg2 << 4) + lr;
          const floatx4 ax = rg2 ? x1 : x0;
#pragma unroll
          for (int g = 0; g < 4; g++) {
            const int m = m0 + (lq << 2) + g;
            const int sum = m + a + 1;
            const int j = sum & 2047;
            const int ri = (sum >= 2048) ? (a - i0) : (a - i0 - 1);
            const int jl = j - J0;
            if ((unsigned)ri < 32u && (unsigned)jl < (unsigned)QW)
              xS[ri * QSTR3 + jl] = (_Float16)(ax[g] * SCL);
          }
        }
      }
    }

    // boundary slice: each thread copies 1 col of this pass from xB
    {
      const int j = J0 + t;
      const bool act = early ? (j <= i0) : (j >= c0);
      if (act) xS[grow * QSTR3 + t] = xB[j - c0];
    }
    // pre-zero the j==i+1 hole of each row (collision-free)
    if (t < 32) {
      const int jl = i0 + t + 1 - J0;
      if ((unsigned)jl < (unsigned)QW) xS[t * QSTR3 + jl] = (_Float16)0.f;
    }
    __syncthreads();   // A: strips complete

    // packed-f16 exp2 in place: row erow, 2 x 16 cols.
    {
      _Float16* qrow = qkS + erow * QSTR3;
      const _Float16* xrow = xS + erow * QSTR3;
      const f16x2 one2 = {(_Float16)1.f, (_Float16)1.f};
#pragma unroll
      for (int ii = 0; ii < 2; ii++) {
        const int cbase = ii * 128 + ecol;
        f16x8 h0 = *(const f16x8*)(qrow + cbase), h1 = *(const f16x8*)(qrow + cbase + 8);
        f16x8 v0 = *(const f16x8*)(xrow + cbase), v1 = *(const f16x8*)(xrow + cbase + 8);
        f16x8 s0 = h0 + v0, s1 = h1 + v1;
        f16x8 p0, p1;
#pragma unroll
        for (int e2 = 0; e2 < 4; e2++) {
          __half2 a2, b2;
          __builtin_memcpy(&a2, (const char*)&s0 + e2 * 4, 4);
          a2 = h2exp2(a2);
          __builtin_memcpy((char*)&p0 + e2 * 4, &a2, 4);
          f16x2 af2; __builtin_memcpy(&af2, &a2, 4);
          psum = __builtin_amdgcn_fdot2(af2, one2, psum, false);
          __builtin_memcpy(&b2, (const char*)&s1 + e2 * 4, 4);
          b2 = h2exp2(b2);
          __builtin_memcpy((char*)&p1 + e2 * 4, &b2, 4);
          f16x2 bf2; __builtin_memcpy(&bf2, &b2, 4);
          psum = __builtin_amdgcn_fdot2(bf2, one2, psum, false);
        }
        *(f16x8*)(qrow + cbase) = p0;
        *(f16x8*)(qrow + cbase + 8) = p1;
      }
    }
    __syncthreads();   // B: p~ complete

    // PV: wave (rg, sl) contracts keys [J0+sl*128, +128) for rows rg*16..+16
#pragma unroll
    for (int ch = 0; ch < 4; ch++) {
      const int kk = sl * 128 + ch * 32;
      f16x8 af = *(const f16x8*)(qkS + (rg * 16 + lr) * QSTR3 + kk + lq * 8);
#pragma unroll
      for (int sub = 0; sub < 4; sub++) {
        f16x8 bfv = *(const f16x8*)(vtz + (long)(sub * 16 + lr) * 2048 + J0 + kk + lq * 8);
        oacc[sub] = __builtin_amdgcn_mfma_f32_16x16x32_f16(af, bfv, oacc[sub], 0, 0, 0);
      }
    }
    __syncthreads();   // C: strip reads done before next pass overwrites
  }

  // fp32 partials overlay the strips (dead after barrier C of last pass)
  {
    float* sPart = (float*)smem;   // [2*rg+sl][16][64]
#pragma unroll
    for (int sub = 0; sub < 4; sub++)
#pragma unroll
      for (int g = 0; g < 4; g++)
        sPart[((rg << 1) + sl) * 1024 + ((lq << 2) + g) * 64 + sub * 16 + lr] = oacc[sub][g];
  }
  // row sums: reduce 8 col-lanes of each row
#pragma unroll
  for (int o = 1; o < 8; o <<= 1) psum += __shfl_xor(psum, o, 64);
  if ((lane & 7) == 0) sInv[erow] = 1.0f / psum;
  __syncthreads();   // D: partials + sInv complete

  // final: 256 threads x 8 outputs (32 rows x 64 d)
  {
    const float* sPart = (const float*)smem;
    const int r = t >> 3, d0 = (t & 7) << 3;
    const int rg2 = r >> 4, rl = r & 15;
    const float inv = sInv[r];
    bf16x8 ov;
#pragma unroll
    for (int e = 0; e < 8; e++) {
      float acc = sPart[(rg2 << 1) * 1024 + rl * 64 + d0 + e] +
                  sPart[((rg2 << 1) + 1) * 1024 + rl * 64 + d0 + e];
      ov[e] = (__bf16)(acc * inv);
    }
    *(bf16x8*)&attnb[((long)b * 2048 + i0 + r) * 1024 + h * 64 + d0] = ov;
  }
}

extern "C" void kernel_launch(void* const* d_in, const int* in_sizes, int n_in,
                              void* d_out, int out_size, void* d_ws, size_t ws_size,
                              hipStream_t stream) {
  (void)in_sizes; (void)n_in; (void)out_size;
  const float* inputs_kv = (const float*)d_in[0];
  const float* inputs_q  = (const float*)d_in[1];
  const float* pos_embed = (const float*)d_in[2];
  const float* Wq_w = (const float*)d_in[3];
  const float* Wq_b = (const float*)d_in[4];
  const float* Wk_w = (const float*)d_in[5];
  const float* Wk_b = (const float*)d_in[6];
  const float* Wv_w = (const float*)d_in[7];
  const float* Wv_b = (const float*)d_in[8];
  const float* Wr_w = (const float*)d_in[9];
  const float* rwb  = (const float*)d_in[10];
  const float* rrb  = (const float*)d_in[11];
  const float* Wo_w = (const float*)d_in[12];
  const float* Wo_b = (const float*)d_in[13];

  char* ws = (char*)d_ws;
  const long MB = 1 << 20;
  __bf16* Wtq = (__bf16*)(ws + 0 * MB);
  __bf16* Wtk = (__bf16*)(ws + 2 * MB);
  __bf16* Wtv = (__bf16*)(ws + 4 * MB);
  __bf16* Wtr = (__bf16*)(ws + 6 * MB);
  __bf16* Wto = (__bf16*)(ws + 8 * MB);
  __bf16* qb  = (__bf16*)(ws + 10 * MB);
  __bf16* qrr = (__bf16*)(ws + 18 * MB);
  __bf16* kb  = (__bf16*)(ws + 26 * MB);
  _Float16* vt = (_Float16*)(ws + 34 * MB);
  __bf16* rb  = (__bf16*)(ws + 42 * MB);
  float*  cb  = (float*)(ws + 46 * MB);               // 256 KB
  __bf16* attnb = (__bf16*)(ws + 47 * MB);            // 8 MB bf16 attention out
  // qinb SHARES the attnb slot: attnb is first written by fused_k, which
  // runs after qkvr_k consumed qinb. Zero extra workspace needed.
  __bf16* qinb  = attnb;
  // kvinb needs its own 8 MB above the baseline 55 MB layout.
  __bf16* kvinb = (__bf16*)(ws + 55 * MB);
  const bool big1 = ws_size >= (size_t)(63 * MB);

  dim3 blk(256);

  TRP tp{};
  tp.src[0] = Wq_w; tp.dst[0] = Wtq;
  tp.src[1] = Wk_w; tp.dst[1] = Wtk;
  tp.src[2] = Wv_w; tp.dst[2] = Wtv;
  tp.src[3] = Wr_w; tp.dst[3] = Wtr;
  tp.src[4] = Wo_w; tp.dst[4] = Wto;
  tp.csrc[0] = inputs_q;  tp.cdst[0] = qinb;  tp.clen[0] = 4096L * 1024;
  tp.csrc[1] = inputs_kv; tp.cdst[1] = kvinb; tp.clen[1] = 4096L * 1024;
  tr_cvt_all<<<dim3(big1 ? 1792 : 1536), blk, 0, stream>>>(tp);

  QPAll q{};
  q.qin = inputs_q; q.kvin = inputs_kv; q.pos = pos_embed;
  q.qinb = qinb; q.kvinb = big1 ? kvinb : nullptr;
  q.Wtq = Wtq; q.Wtk = Wtk; q.Wtv = Wtv; q.Wtr = Wtr;
  q.bq = Wq_b; q.bk = Wk_b; q.bv = Wv_b; q.rrb = rrb;
  q.qb = qb; q.qrr = qrr; q.kb = kb; q.rb = rb; q.vt = vt;
  qkvr_k<<<dim3(896), blk, 0, stream>>>(q);

  cb_k<<<dim3(256), blk, 0, stream>>>(kb, rwb, cb);

  fused_k<<<dim3(2048), dim3(256), FUSED_SMEM, stream>>>(qb, qrr, kb, vt, rb, cb, attnb);

  // Output projection: d_out = attn(bf16) @ Wo + bo
  GP o{};
  o.A = attnb; o.B = Wto; o.lda = 1024; o.ldb = 1024; o.K = 1024;
  o.bias = Wo_b; o.outF = (float*)d_out;
  gemm_o<<<dim3(8, 64), blk, 0, stream>>>(o);
}

// Round 12
// 509.061 us; speedup vs baseline: 1.0280x; 1.0280x over previous
//
#include <hip/hip_runtime.h>
#include <hip/hip_fp16.h>

// RelMultiHeadAttention (Transformer-XL) on gfx950.
// B=2, S=2048, D=1024, H=16, hd=64.
// R18 = exact R14 (champion, measured 507.6us total / 293us fused).
// R15-R17 explored GEMM-side staging (global_load_lds crash; linear-LDS
// null; bf16-A + gemm_o retile regression) — all reverted. fused_k: 4-wave
// blocks, 32 q-rows, 8 j-passes of width 256, packed-f16 exp2 softmax
// (log2(e) folded into all score scales), pre-zeroed j==i+1 hole, LDS
// boundary row, XCD swizzle. 3 barriers/pass.

typedef float  floatx4 __attribute__((ext_vector_type(4)));
typedef __bf16 bf16x8  __attribute__((ext_vector_type(8)));
typedef _Float16 f16x8 __attribute__((ext_vector_type(8)));
typedef _Float16 f16x4 __attribute__((ext_vector_type(4)));
typedef _Float16 f16x2 __attribute__((ext_vector_type(2)));

#define LSTR 40   // proj-GEMM LDS row stride (bf16): conflict-free b128
#define SCL 0.18033688f   // 0.125 * log2(e): score scale with exp->exp2 fold

struct GP {
  const void* A;
  const __bf16* B;
  int lda, ldb, K;
  float* outF;
  __bf16* out1;
  const float* bias;
};

// Output projection only (attn bf16 @ Wo + bo -> f32)
__global__ void __launch_bounds__(256) gemm_o(GP p) {
  __shared__ __bf16 lA[128 * LSTR];
  __shared__ __bf16 lB[128 * LSTR];
  const int t = threadIdx.x;
  const int wave = t >> 6, lane = t & 63;
  const int m0 = blockIdx.y * 128, n0 = blockIdx.x * 128;
  const int srow = t >> 2, scol = (t & 3) << 3;
  const __bf16* Ab = (const __bf16*)p.A;
  const __bf16* Bb = p.B;

  floatx4 acc[4][4];
#pragma unroll
  for (int i = 0; i < 4; i++)
#pragma unroll
    for (int j = 0; j < 4; j++) acc[i][j] = floatx4{0.f, 0.f, 0.f, 0.f};

  const int lr = lane & 15, lq = lane >> 4;
  const int wr = (wave >> 1) << 6, wc = (wave & 1) << 6;

  for (int kk = 0; kk < p.K; kk += 32) {
#pragma unroll
    for (int h2 = 0; h2 < 2; h2++) {
      int r = srow + (h2 << 6);
      const __bf16* ap = Ab + (long)(m0 + r) * p.lda + kk + scol;
      *(bf16x8*)&lA[r * LSTR + scol] = *(const bf16x8*)ap;
      const __bf16* bp = Bb + (long)(n0 + r) * p.ldb + kk + scol;
      *(bf16x8*)&lB[r * LSTR + scol] = *(const bf16x8*)bp;
    }
    __syncthreads();
    bf16x8 aF[4], bF[4];
#pragma unroll
    for (int i = 0; i < 4; i++)
      aF[i] = *(bf16x8*)&lA[(wr + i * 16 + lr) * LSTR + (lq << 3)];
#pragma unroll
    for (int i = 0; i < 4; i++)
      bF[i] = *(bf16x8*)&lB[(wc + i * 16 + lr) * LSTR + (lq << 3)];
#pragma unroll
    for (int i = 0; i < 4; i++)
#pragma unroll
      for (int j = 0; j < 4; j++)
        acc[i][j] = __builtin_amdgcn_mfma_f32_16x16x32_bf16(aF[i], bF[j], acc[i][j], 0, 0, 0);
    __syncthreads();
  }
#pragma unroll
  for (int i = 0; i < 4; i++)
#pragma unroll
    for (int j = 0; j < 4; j++) {
      int col = n0 + wc + j * 16 + lr;
#pragma unroll
      for (int g = 0; g < 4; g++) {
        int rl = m0 + wr + i * 16 + (lq << 2) + g;
        p.outF[(long)rl * 1024 + col] = acc[i][j][g] + p.bias[col];
      }
    }
}

// ---- merged Q/K/V/R projection: one launch, job table ----------------------
struct QPAll {
  const float *qin, *kvin, *pos;
  const __bf16 *Wtq, *Wtk, *Wtv, *Wtr;
  const float *bq, *bk, *bv, *rrb;
  __bf16 *qb, *qrr, *kb, *rb;
  _Float16 *vt;
};

__global__ void __launch_bounds__(256, 3) qkvr_k(QPAll p) {
  __shared__ __bf16 lA[128 * LSTR];
  __shared__ __bf16 lB[128 * LSTR];
  const int jb = blockIdx.x;
  const int job = (jb >= 768) ? 3 : (jb >> 8);
  const int local = jb - ((job == 3) ? 768 : (job << 8));
  const int m0 = (local >> 3) * 128, n0 = (local & 7) * 128;

  const float* A; const __bf16* B; const float* bias;
  if (job == 0)      { A = p.qin;  B = p.Wtq; bias = p.bq; }
  else if (job == 1) { A = p.kvin; B = p.Wtk; bias = p.bk; }
  else if (job == 2) { A = p.kvin; B = p.Wtv; bias = p.bv; }
  else               { A = p.pos;  B = p.Wtr; bias = nullptr; }

  const int t = threadIdx.x;
  const int wave = t >> 6, lane = t & 63;
  const int srow = t >> 2, scol = (t & 3) << 3;

  floatx4 acc[4][4];
#pragma unroll
  for (int i = 0; i < 4; i++)
#pragma unroll
    for (int j = 0; j < 4; j++) acc[i][j] = floatx4{0.f, 0.f, 0.f, 0.f};

  const int lr = lane & 15, lq = lane >> 4;
  const int wr = (wave >> 1) << 6, wc = (wave & 1) << 6;

  for (int kk = 0; kk < 1024; kk += 32) {
#pragma unroll
    for (int h2 = 0; h2 < 2; h2++) {
      int r = srow + (h2 << 6);
      const float* ap = A + (long)(m0 + r) * 1024 + kk + scol;
      float4 f0 = *(const float4*)ap;
      float4 f1 = *(const float4*)(ap + 4);
      bf16x8 o;
      o[0] = (__bf16)f0.x; o[1] = (__bf16)f0.y; o[2] = (__bf16)f0.z; o[3] = (__bf16)f0.w;
      o[4] = (__bf16)f1.x; o[5] = (__bf16)f1.y; o[6] = (__bf16)f1.z; o[7] = (__bf16)f1.w;
      *(bf16x8*)&lA[r * LSTR + scol] = o;
      const __bf16* bp = B + (long)(n0 + r) * 1024 + kk + scol;
      *(bf16x8*)&lB[r * LSTR + scol] = *(const bf16x8*)bp;
    }
    __syncthreads();
    bf16x8 aF[4], bF[4];
#pragma unroll
    for (int i = 0; i < 4; i++)
      aF[i] = *(bf16x8*)&lA[(wr + i * 16 + lr) * LSTR + (lq << 3)];
#pragma unroll
    for (int i = 0; i < 4; i++)
      bF[i] = *(bf16x8*)&lB[(wc + i * 16 + lr) * LSTR + (lq << 3)];
#pragma unroll
    for (int i = 0; i < 4; i++)
#pragma unroll
      for (int j = 0; j < 4; j++)
        acc[i][j] = __builtin_amdgcn_mfma_f32_16x16x32_bf16(aF[i], bF[j], acc[i][j], 0, 0, 0);
    __syncthreads();
  }

  // epilogue per job; C/D: col=lane&15, row=(lane>>4)*4+reg
#pragma unroll
  for (int i = 0; i < 4; i++)
#pragma unroll
    for (int j = 0; j < 4; j++) {
      int col = n0 + wc + j * 16 + lr;
#pragma unroll
      for (int g = 0; g < 4; g++) {
        int rl = m0 + wr + i * 16 + (lq << 2) + g;
        float val = acc[i][j][g];
        int hh = col >> 6, d = col & 63;
        if (job == 3) {
          long dst = (((long)hh * 2048 + rl) << 6) + d;
          p.rb[dst] = (__bf16)val;
        } else {
          int bb = rl >> 11, s = rl & 2047;
          float v = val + bias[col];
          if (job == 0) {
            long dst = (((long)(bb * 16 + hh) * 2048 + s) << 6) + d;
            p.qb[dst] = (__bf16)v;
            p.qrr[dst] = (__bf16)(v + p.rrb[col]);
          } else if (job == 1) {
            long dst = (((long)(bb * 16 + hh) * 2048 + s) << 6) + d;
            p.kb[dst] = (__bf16)v;
          } else {
            long dst = ((((long)(bb * 16 + hh)) << 6) + d) * 2048 + s;
            p.vt[dst] = (_Float16)v;
          }
        }
      }
    }
}

// cb pre-scaled by 0.125*log2(e) so fused exp2 needs no extra factor.
__global__ void __launch_bounds__(256) cb_k(const __bf16* kb, const float* rwb, float* cb) {
  long id = (long)blockIdx.x * 256 + threadIdx.x;  // 32*2048
  int z = (int)(id >> 11);
  int j = (int)(id & 2047);
  int h = z & 15;
  const __bf16* kp = kb + (((long)z * 2048 + j) << 6);
  float s = 0.f;
#pragma unroll
  for (int c = 0; c < 8; c++) {
    bf16x8 kv = *(const bf16x8*)(kp + c * 8);
#pragma unroll
    for (int e = 0; e < 8; e++) s += rwb[h * 64 + c * 8 + e] * (float)kv[e];
  }
  cb[id] = s * SCL;
}

// All five weight transposes in one launch: 5 x 256 tiles.
struct TRP { const float* src[5]; __bf16* dst[5]; };
__global__ void __launch_bounds__(256) tr_cvt_all(TRP p) {
  __shared__ float tile[64][65];
  const int id = blockIdx.x;
  const int which = id >> 8;
  const int local = id & 255;
  const int bx = local & 15, by = local >> 4;
  const float* src = p.src[which];
  __bf16* dst = p.dst[which];
  int tx = threadIdx.x & 63, ty = threadIdx.x >> 6;
#pragma unroll
  for (int r = ty; r < 64; r += 4)
    tile[r][tx] = src[(long)(by * 64 + r) * 1024 + bx * 64 + tx];
  __syncthreads();
#pragma unroll
  for (int r = ty; r < 64; r += 4)
    dst[(long)(bx * 64 + r) * 1024 + by * 64 + tx] = (__bf16)tile[tx][r];
}

// -------- fused scores + rel-shift + softmax + PV: 4-wave blocks -----------
// 32 q-rows/block, 8 j-passes of width 256. Strips [32][QSTR3] f16 (qk, x)
// + xB[1024] f16. Per pass: qk+x MFMA + boundary copy + j==i+1 pre-zero ->
// barrier A -> packed-f16 exp2 in place -> barrier B -> PV -> barrier C.
#define QW 256
#define QSTR3 264                         // row stride f16 (256+8)
#define SM_ONE (32 * QSTR3 * 2)           // 16896 B per strip
#define FUSED_SMEM (2 * SM_ONE + 2048)    // 35840 B -> 4 blocks/CU

__global__ void __launch_bounds__(256, 4) fused_k(const __bf16* __restrict__ qb,
                                                  const __bf16* __restrict__ qrr,
                                                  const __bf16* __restrict__ kb,
                                                  const _Float16* __restrict__ vt,
                                                  const __bf16* __restrict__ rb,
                                                  const float* __restrict__ cb,
                                                  __bf16* __restrict__ attnb) {
  extern __shared__ char smem[];
  _Float16* qkS = (_Float16*)smem;              // [32][QSTR3]
  _Float16* xS  = (_Float16*)(smem + SM_ONE);   // [32][QSTR3]
  _Float16* xB  = (_Float16*)(smem + 2 * SM_ONE);  // [1024] boundary row
  __shared__ float sInv[32];

  const int t = threadIdx.x;
  const int w = t >> 6, lane = t & 63, lr = lane & 15, lq = lane >> 4;
  // XCD swizzle: all 64 tiles of a (b,h) on one XCD.
  const int obid = blockIdx.x;
  const int bid = ((obid & 7) << 8) | (obid >> 3);
  const int z  = bid >> 6;
  const int i0 = (bid & 63) << 5;
  const int b = z >> 4, h = z & 15;
  const bool early = (i0 <= 1023);
  const int astart = early ? i0 + 1 : i0;   // 32 MFMA x-rows [astart, astart+32)
  const int grow = early ? 0 : 31;          // boundary strip row
  const int c0   = early ? 0 : i0 + 33;     // boundary col range start

  // B-frags: q rows i0+rg*16+lr, qrr rows astart+rg*16+lr
  bf16x8 fq[2][2], fr[2][2];
#pragma unroll
  for (int rg2 = 0; rg2 < 2; rg2++) {
    const __bf16* qp = qb + (((long)z * 2048 + i0 + rg2 * 16 + lr) << 6) + lq * 8;
    fq[rg2][0] = *(const bf16x8*)qp; fq[rg2][1] = *(const bf16x8*)(qp + 32);
    const __bf16* rp = qrr + (((long)z * 2048 + astart + rg2 * 16 + lr) << 6) + lq * 8;
    fr[rg2][0] = *(const bf16x8*)rp; fr[rg2][1] = *(const bf16x8*)(rp + 32);
  }

  const __bf16* kbz = kb + (((long)z * 2048) << 6);
  const __bf16* rbh = rb + (((long)h * 2048) << 6);
  const float* cbz = cb + (long)z * 2048;
  const _Float16* vtz = vt + (((long)z) << 6) * 2048;

  // ---- boundary row, once per block, coalesced: 8 lanes per column --------
  {
    const int ga    = early ? i0 : i0 + 32;
    const int m0g   = early ? (2047 - i0) : 0;
    int ncols = early ? (i0 + 1) : (2015 - i0);
    if (ncols < 0) ncols = 0;
    const int dl = (t & 7) << 3;          // 8 d's per lane
    bf16x8 qv = *(const bf16x8*)(qrr + (((long)z * 2048 + ga) << 6) + dl);
    for (int c = t >> 3; c < ncols; c += 32) {
      bf16x8 rv = *(const bf16x8*)(rbh + ((long)(m0g + c) << 6) + dl);
      float s = 0.f;
#pragma unroll
      for (int e = 0; e < 8; e++) s += (float)qv[e] * (float)rv[e];
      s += __shfl_xor(s, 1, 64);
      s += __shfl_xor(s, 2, 64);
      s += __shfl_xor(s, 4, 64);
      if ((t & 7) == 0) xB[c] = (_Float16)(s * SCL);
    }
  }
  __syncthreads();   // xB visible to all waves

  const int erow = w * 8 + (lane >> 3);     // exp row for this lane
  const int ecol = (lane & 7) * 16;         // exp col base within half-pass
  const int rg = w >> 1, sl = w & 1;        // PV role: row-group, k-slice

  floatx4 oacc[4];
#pragma unroll
  for (int s = 0; s < 4; s++) oacc[s] = floatx4{0.f, 0.f, 0.f, 0.f};
  float psum = 0.f;

  for (int kp = 0; kp < 8; kp++) {
    const int J0 = kp << 8;

    // qk MFMA (+cb fold): 16 j-tiles, wave does 4. D: row=key-local, col=q-row.
#pragma unroll
    for (int s = 0; s < 4; s++) {
      const int jt = ((w << 2) + s) << 4;     // 0..240
      const __bf16* ap = kbz + ((long)(J0 + jt + lr) << 6) + lq * 8;
      bf16x8 a0 = *(const bf16x8*)ap, a1 = *(const bf16x8*)(ap + 32);
      floatx4 cbv = *(const floatx4*)(cbz + J0 + jt + lq * 4);
      floatx4 c0v{0.f, 0.f, 0.f, 0.f}, c1v{0.f, 0.f, 0.f, 0.f};
      c0v = __builtin_amdgcn_mfma_f32_16x16x32_bf16(a0, fq[0][0], c0v, 0, 0, 0);
      c0v = __builtin_amdgcn_mfma_f32_16x16x32_bf16(a1, fq[0][1], c0v, 0, 0, 0);
      c1v = __builtin_amdgcn_mfma_f32_16x16x32_bf16(a0, fq[1][0], c1v, 0, 0, 0);
      c1v = __builtin_amdgcn_mfma_f32_16x16x32_bf16(a1, fq[1][1], c1v, 0, 0, 0);
      f16x4 s0v, s1v;
#pragma unroll
      for (int g = 0; g < 4; g++) {
        s0v[g] = (_Float16)(c0v[g] * SCL + cbv[g]);
        s1v[g] = (_Float16)(c1v[g] * SCL + cbv[g]);
      }
      *(f16x4*)&qkS[lr * QSTR3 + jt + lq * 4] = s0v;
      *(f16x4*)&qkS[(16 + lr) * QSTR3 + jt + lq * 4] = s1v;
    }

    // x MFMA: m-window = 287 consecutive values -> <=19 tiles over 4 waves;
    // wave-uniform predicate. Scatter with shift pre-applied.
    const int mb = ((J0 - astart - 32) & 2047) & ~15;
#pragma unroll
    for (int s = 0; s < 5; s++) {
      const int mt = w + (s << 2);
      if (mt < 19) {
        const int m0 = (mb + (mt << 4)) & 2047;
        const __bf16* rp2 = rbh + ((long)(m0 + lr) << 6) + lq * 8;
        bf16x8 r0 = *(const bf16x8*)rp2, r1 = *(const bf16x8*)(rp2 + 32);
        floatx4 x0{0.f, 0.f, 0.f, 0.f}, x1{0.f, 0.f, 0.f, 0.f};
        x0 = __builtin_amdgcn_mfma_f32_16x16x32_bf16(r0, fr[0][0], x0, 0, 0, 0);
        x0 = __builtin_amdgcn_mfma_f32_16x16x32_bf16(r1, fr[0][1], x0, 0, 0, 0);
        x1 = __builtin_amdgcn_mfma_f32_16x16x32_bf16(r0, fr[1][0], x1, 0, 0, 0);
        x1 = __builtin_amdgcn_mfma_f32_16x16x32_bf16(r1, fr[1][1], x1, 0, 0, 0);
#pragma unroll
        for (int rg2 = 0; rg2 < 2; rg2++) {
          const int a = astart + (rg2 << 4) + lr;
          const floatx4 ax = rg2 ? x1 : x0;
#pragma unroll
          for (int g = 0; g < 4; g++) {
            const int m = m0 + (lq << 2) + g;
            const int sum = m + a + 1;
            const int j = sum & 2047;
            const int ri = (sum >= 2048) ? (a - i0) : (a - i0 - 1);
            const int jl = j - J0;
            if ((unsigned)ri < 32u && (unsigned)jl < (unsigned)QW)
              xS[ri * QSTR3 + jl] = (_Float16)(ax[g] * SCL);
          }
        }
      }
    }

    // boundary slice: each thread copies 1 col of this pass from xB
    {
      const int j = J0 + t;
      const bool act = early ? (j <= i0) : (j >= c0);
      if (act) xS[grow * QSTR3 + t] = xB[j - c0];
    }
    // pre-zero the j==i+1 hole of each row (collision-free: no scatter or
    // boundary-copy write ever targets (row i, col i+1))
    if (t < 32) {
      const int jl = i0 + t + 1 - J0;
      if ((unsigned)jl < (unsigned)QW) xS[t * QSTR3 + jl] = (_Float16)0.f;
    }
    __syncthreads();   // A: strips complete

    // packed-f16 exp2 in place: row erow, 2 x 16 cols. No selects, no index
    // math: score+x via v_pk_add_f16, exp2 via v_exp_f16, psum via fdot2.
    {
      _Float16* qrow = qkS + erow * QSTR3;
      const _Float16* xrow = xS + erow * QSTR3;
      const f16x2 one2 = {(_Float16)1.f, (_Float16)1.f};
#pragma unroll
      for (int ii = 0; ii < 2; ii++) {
        const int cbase = ii * 128 + ecol;
        f16x8 h0 = *(const f16x8*)(qrow + cbase), h1 = *(const f16x8*)(qrow + cbase + 8);
        f16x8 v0 = *(const f16x8*)(xrow + cbase), v1 = *(const f16x8*)(xrow + cbase + 8);
        f16x8 s0 = h0 + v0, s1 = h1 + v1;
        f16x8 p0, p1;
#pragma unroll
        for (int e2 = 0; e2 < 4; e2++) {
          __half2 a2, b2;
          __builtin_memcpy(&a2, (const char*)&s0 + e2 * 4, 4);
          a2 = h2exp2(a2);
          __builtin_memcpy((char*)&p0 + e2 * 4, &a2, 4);
          f16x2 af2; __builtin_memcpy(&af2, &a2, 4);
          psum = __builtin_amdgcn_fdot2(af2, one2, psum, false);
          __builtin_memcpy(&b2, (const char*)&s1 + e2 * 4, 4);
          b2 = h2exp2(b2);
          __builtin_memcpy((char*)&p1 + e2 * 4, &b2, 4);
          f16x2 bf2; __builtin_memcpy(&bf2, &b2, 4);
          psum = __builtin_amdgcn_fdot2(bf2, one2, psum, false);
        }
        *(f16x8*)(qrow + cbase) = p0;
        *(f16x8*)(qrow + cbase + 8) = p1;
      }
    }
    __syncthreads();   // B: p~ complete

    // PV: wave (rg, sl) contracts keys [J0+sl*128, +128) for rows rg*16..+16
#pragma unroll
    for (int ch = 0; ch < 4; ch++) {
      const int kk = sl * 128 + ch * 32;
      f16x8 af = *(const f16x8*)(qkS + (rg * 16 + lr) * QSTR3 + kk + lq * 8);
#pragma unroll
      for (int sub = 0; sub < 4; sub++) {
        f16x8 bfv = *(const f16x8*)(vtz + (long)(sub * 16 + lr) * 2048 + J0 + kk + lq * 8);
        oacc[sub] = __builtin_amdgcn_mfma_f32_16x16x32_f16(af, bfv, oacc[sub], 0, 0, 0);
      }
    }
    __syncthreads();   // C: strip reads done before next pass overwrites
  }

  // fp32 partials overlay the strips (dead after barrier C of last pass)
  {
    float* sPart = (float*)smem;   // [2*rg+sl][16][64]
#pragma unroll
    for (int sub = 0; sub < 4; sub++)
#pragma unroll
      for (int g = 0; g < 4; g++)
        sPart[((rg << 1) + sl) * 1024 + ((lq << 2) + g) * 64 + sub * 16 + lr] = oacc[sub][g];
  }
  // row sums: reduce 8 col-lanes of each row
#pragma unroll
  for (int o = 1; o < 8; o <<= 1) psum += __shfl_xor(psum, o, 64);
  if ((lane & 7) == 0) sInv[erow] = 1.0f / psum;
  __syncthreads();   // D: partials + sInv complete

  // final: 256 threads x 8 outputs (32 rows x 64 d)
  {
    const float* sPart = (const float*)smem;
    const int r = t >> 3, d0 = (t & 7) << 3;
    const int rg2 = r >> 4, rl = r & 15;
    const float inv = sInv[r];
    bf16x8 ov;
#pragma unroll
    for (int e = 0; e < 8; e++) {
      float acc = sPart[(rg2 << 1) * 1024 + rl * 64 + d0 + e] +
                  sPart[((rg2 << 1) + 1) * 1024 + rl * 64 + d0 + e];
      ov[e] = (__bf16)(acc * inv);
    }
    *(bf16x8*)&attnb[((long)b * 2048 + i0 + r) * 1024 + h * 64 + d0] = ov;
  }
}

extern "C" void kernel_launch(void* const* d_in, const int* in_sizes, int n_in,
                              void* d_out, int out_size, void* d_ws, size_t ws_size,
                              hipStream_t stream) {
  (void)in_sizes; (void)n_in; (void)out_size; (void)ws_size;
  const float* inputs_kv = (const float*)d_in[0];
  const float* inputs_q  = (const float*)d_in[1];
  const float* pos_embed = (const float*)d_in[2];
  const float* Wq_w = (const float*)d_in[3];
  const float* Wq_b = (const float*)d_in[4];
  const float* Wk_w = (const float*)d_in[5];
  const float* Wk_b = (const float*)d_in[6];
  const float* Wv_w = (const float*)d_in[7];
  const float* Wv_b = (const float*)d_in[8];
  const float* Wr_w = (const float*)d_in[9];
  const float* rwb  = (const float*)d_in[10];
  const float* rrb  = (const float*)d_in[11];
  const float* Wo_w = (const float*)d_in[12];
  const float* Wo_b = (const float*)d_in[13];

  char* ws = (char*)d_ws;
  const long MB = 1 << 20;
  __bf16* Wtq = (__bf16*)(ws + 0 * MB);
  __bf16* Wtk = (__bf16*)(ws + 2 * MB);
  __bf16* Wtv = (__bf16*)(ws + 4 * MB);
  __bf16* Wtr = (__bf16*)(ws + 6 * MB);
  __bf16* Wto = (__bf16*)(ws + 8 * MB);
  __bf16* qb  = (__bf16*)(ws + 10 * MB);
  __bf16* qrr = (__bf16*)(ws + 18 * MB);
  __bf16* kb  = (__bf16*)(ws + 26 * MB);
  _Float16* vt = (_Float16*)(ws + 34 * MB);
  __bf16* rb  = (__bf16*)(ws + 42 * MB);
  float*  cb  = (float*)(ws + 46 * MB);               // 256 KB
  __bf16* attnb = (__bf16*)(ws + 47 * MB);            // 8 MB bf16 attention out

  dim3 blk(256);

  TRP tp{};
  tp.src[0] = Wq_w; tp.dst[0] = Wtq;
  tp.src[1] = Wk_w; tp.dst[1] = Wtk;
  tp.src[2] = Wv_w; tp.dst[2] = Wtv;
  tp.src[3] = Wr_w; tp.dst[3] = Wtr;
  tp.src[4] = Wo_w; tp.dst[4] = Wto;
  tr_cvt_all<<<dim3(1280), blk, 0, stream>>>(tp);

  QPAll q{};
  q.qin = inputs_q; q.kvin = inputs_kv; q.pos = pos_embed;
  q.Wtq = Wtq; q.Wtk = Wtk; q.Wtv = Wtv; q.Wtr = Wtr;
  q.bq = Wq_b; q.bk = Wk_b; q.bv = Wv_b; q.rrb = rrb;
  q.qb = qb; q.qrr = qrr; q.kb = kb; q.rb = rb; q.vt = vt;
  qkvr_k<<<dim3(896), blk, 0, stream>>>(q);

  cb_k<<<dim3(256), blk, 0, stream>>>(kb, rwb, cb);

  fused_k<<<dim3(2048), dim3(256), FUSED_SMEM, stream>>>(qb, qrr, kb, vt, rb, cb, attnb);

  // Output projection: d_out = attn(bf16) @ Wo + bo
  GP o{};
  o.A = attnb; o.B = Wto; o.lda = 1024; o.ldb = 1024; o.K = 1024;
  o.bias = Wo_b; o.outF = (float*)d_out;
  gemm_o<<<dim3(8, 32), blk, 0, stream>>>(o);
}

// Round 13
// 503.136 us; speedup vs baseline: 1.0401x; 1.0118x over previous
//
#include <hip/hip_runtime.h>
#include <hip/hip_fp16.h>

// RelMultiHeadAttention (Transformer-XL) on gfx950.
// B=2, S=2048, D=1024, H=16, hd=64.
// R19 = R18 champion (509us) + ONE isolated change: gemm_o retiled
// 128x128 -> 64x128 (512 blocks = 2 blocks/CU, 8 waves/CU; was 1 block/CU
// = 12% occupancy, pure latency exposure). Per-output MFMA chain identical
// => bit-identical result (hardware-verified in R17's passing run). This
// isolates the R17 confound: its +13us bundled this retile with a
// traffic-negative cvt-prepass (pre-converting once-read data adds a full
// pass: 32MB vs 16MB) — the prepass is dropped permanently.
// fused_k FROZEN at R14: 4-wave blocks, 32 q-rows, 8 j-passes of width 256,
// packed-f16 exp2 softmax, pre-zeroed j==i+1 hole, LDS boundary row,
// XCD swizzle, 3 barriers/pass.

typedef float  floatx4 __attribute__((ext_vector_type(4)));
typedef __bf16 bf16x8  __attribute__((ext_vector_type(8)));
typedef _Float16 f16x8 __attribute__((ext_vector_type(8)));
typedef _Float16 f16x4 __attribute__((ext_vector_type(4)));
typedef _Float16 f16x2 __attribute__((ext_vector_type(2)));

#define LSTR 40   // proj-GEMM LDS row stride (bf16): conflict-free b128
#define SCL 0.18033688f   // 0.125 * log2(e): score scale with exp->exp2 fold

struct GP {
  const void* A;
  const __bf16* B;
  int lda, ldb, K;
  float* outF;
  __bf16* out1;
  const float* bias;
};

// Output projection (attn bf16 @ Wo + bo -> f32), 64x128 tiles, 512 blocks.
__global__ void __launch_bounds__(256) gemm_o(GP p) {
  __shared__ __align__(16) __bf16 lA[64 * 32];
  __shared__ __align__(16) __bf16 lB[128 * 32];
  const int t = threadIdx.x;
  const int wave = t >> 6, lane = t & 63;
  const int m0 = blockIdx.y * 64, n0 = blockIdx.x * 128;
  const __bf16* Ab = (const __bf16*)p.A;
  const __bf16* Bb = p.B;

  floatx4 acc[2][4];
#pragma unroll
  for (int i = 0; i < 2; i++)
#pragma unroll
    for (int j = 0; j < 4; j++) acc[i][j] = floatx4{0.f, 0.f, 0.f, 0.f};

  const int lr = lane & 15, lq = lane >> 4;
  const int wr = (wave >> 1) << 5, wc = (wave & 1) << 6;

  for (int kk = 0; kk < 1024; kk += 32) {
    {
      const int row = t >> 2, ch = (t & 3) << 3;   // 64 rows x 4 chunks
      *(bf16x8*)&lA[row * 32 + ch] = *(const bf16x8*)(Ab + (long)(m0 + row) * 1024 + kk + ch);
    }
#pragma unroll
    for (int i = 0; i < 2; i++) {
      const int idx = (i << 8) + t;                // 0..511 -> 128 rows
      const int row = idx >> 2, ch = (idx & 3) << 3;
      *(bf16x8*)&lB[row * 32 + ch] = *(const bf16x8*)(Bb + (long)(n0 + row) * 1024 + kk + ch);
    }
    __syncthreads();
    bf16x8 aF[2], bF[4];
#pragma unroll
    for (int i = 0; i < 2; i++)
      aF[i] = *(bf16x8*)&lA[(wr + i * 16 + lr) * 32 + (lq << 3)];
#pragma unroll
    for (int j = 0; j < 4; j++)
      bF[j] = *(bf16x8*)&lB[(wc + j * 16 + lr) * 32 + (lq << 3)];
#pragma unroll
    for (int i = 0; i < 2; i++)
#pragma unroll
      for (int j = 0; j < 4; j++)
        acc[i][j] = __builtin_amdgcn_mfma_f32_16x16x32_bf16(aF[i], bF[j], acc[i][j], 0, 0, 0);
    __syncthreads();
  }
#pragma unroll
  for (int i = 0; i < 2; i++)
#pragma unroll
    for (int j = 0; j < 4; j++) {
      int col = n0 + wc + j * 16 + lr;
#pragma unroll
      for (int g = 0; g < 4; g++) {
        int rl = m0 + wr + i * 16 + (lq << 2) + g;
        p.outF[(long)rl * 1024 + col] = acc[i][j][g] + p.bias[col];
      }
    }
}

// ---- merged Q/K/V/R projection: one launch, job table ----------------------
struct QPAll {
  const float *qin, *kvin, *pos;
  const __bf16 *Wtq, *Wtk, *Wtv, *Wtr;
  const float *bq, *bk, *bv, *rrb;
  __bf16 *qb, *qrr, *kb, *rb;
  _Float16 *vt;
};

__global__ void __launch_bounds__(256, 3) qkvr_k(QPAll p) {
  __shared__ __bf16 lA[128 * LSTR];
  __shared__ __bf16 lB[128 * LSTR];
  const int jb = blockIdx.x;
  const int job = (jb >= 768) ? 3 : (jb >> 8);
  const int local = jb - ((job == 3) ? 768 : (job << 8));
  const int m0 = (local >> 3) * 128, n0 = (local & 7) * 128;

  const float* A; const __bf16* B; const float* bias;
  if (job == 0)      { A = p.qin;  B = p.Wtq; bias = p.bq; }
  else if (job == 1) { A = p.kvin; B = p.Wtk; bias = p.bk; }
  else if (job == 2) { A = p.kvin; B = p.Wtv; bias = p.bv; }
  else               { A = p.pos;  B = p.Wtr; bias = nullptr; }

  const int t = threadIdx.x;
  const int wave = t >> 6, lane = t & 63;
  const int srow = t >> 2, scol = (t & 3) << 3;

  floatx4 acc[4][4];
#pragma unroll
  for (int i = 0; i < 4; i++)
#pragma unroll
    for (int j = 0; j < 4; j++) acc[i][j] = floatx4{0.f, 0.f, 0.f, 0.f};

  const int lr = lane & 15, lq = lane >> 4;
  const int wr = (wave >> 1) << 6, wc = (wave & 1) << 6;

  for (int kk = 0; kk < 1024; kk += 32) {
#pragma unroll
    for (int h2 = 0; h2 < 2; h2++) {
      int r = srow + (h2 << 6);
      const float* ap = A + (long)(m0 + r) * 1024 + kk + scol;
      float4 f0 = *(const float4*)ap;
      float4 f1 = *(const float4*)(ap + 4);
      bf16x8 o;
      o[0] = (__bf16)f0.x; o[1] = (__bf16)f0.y; o[2] = (__bf16)f0.z; o[3] = (__bf16)f0.w;
      o[4] = (__bf16)f1.x; o[5] = (__bf16)f1.y; o[6] = (__bf16)f1.z; o[7] = (__bf16)f1.w;
      *(bf16x8*)&lA[r * LSTR + scol] = o;
      const __bf16* bp = B + (long)(n0 + r) * 1024 + kk + scol;
      *(bf16x8*)&lB[r * LSTR + scol] = *(const bf16x8*)bp;
    }
    __syncthreads();
    bf16x8 aF[4], bF[4];
#pragma unroll
    for (int i = 0; i < 4; i++)
      aF[i] = *(bf16x8*)&lA[(wr + i * 16 + lr) * LSTR + (lq << 3)];
#pragma unroll
    for (int i = 0; i < 4; i++)
      bF[i] = *(bf16x8*)&lB[(wc + i * 16 + lr) * LSTR + (lq << 3)];
#pragma unroll
    for (int i = 0; i < 4; i++)
#pragma unroll
      for (int j = 0; j < 4; j++)
        acc[i][j] = __builtin_amdgcn_mfma_f32_16x16x32_bf16(aF[i], bF[j], acc[i][j], 0, 0, 0);
    __syncthreads();
  }

  // epilogue per job; C/D: col=lane&15, row=(lane>>4)*4+reg
#pragma unroll
  for (int i = 0; i < 4; i++)
#pragma unroll
    for (int j = 0; j < 4; j++) {
      int col = n0 + wc + j * 16 + lr;
#pragma unroll
      for (int g = 0; g < 4; g++) {
        int rl = m0 + wr + i * 16 + (lq << 2) + g;
        float val = acc[i][j][g];
        int hh = col >> 6, d = col & 63;
        if (job == 3) {
          long dst = (((long)hh * 2048 + rl) << 6) + d;
          p.rb[dst] = (__bf16)val;
        } else {
          int bb = rl >> 11, s = rl & 2047;
          float v = val + bias[col];
          if (job == 0) {
            long dst = (((long)(bb * 16 + hh) * 2048 + s) << 6) + d;
            p.qb[dst] = (__bf16)v;
            p.qrr[dst] = (__bf16)(v + p.rrb[col]);
          } else if (job == 1) {
            long dst = (((long)(bb * 16 + hh) * 2048 + s) << 6) + d;
            p.kb[dst] = (__bf16)v;
          } else {
            long dst = ((((long)(bb * 16 + hh)) << 6) + d) * 2048 + s;
            p.vt[dst] = (_Float16)v;
          }
        }
      }
    }
}

// cb pre-scaled by 0.125*log2(e) so fused exp2 needs no extra factor.
__global__ void __launch_bounds__(256) cb_k(const __bf16* kb, const float* rwb, float* cb) {
  long id = (long)blockIdx.x * 256 + threadIdx.x;  // 32*2048
  int z = (int)(id >> 11);
  int j = (int)(id & 2047);
  int h = z & 15;
  const __bf16* kp = kb + (((long)z * 2048 + j) << 6);
  float s = 0.f;
#pragma unroll
  for (int c = 0; c < 8; c++) {
    bf16x8 kv = *(const bf16x8*)(kp + c * 8);
#pragma unroll
    for (int e = 0; e < 8; e++) s += rwb[h * 64 + c * 8 + e] * (float)kv[e];
  }
  cb[id] = s * SCL;
}

// All five weight transposes in one launch: 5 x 256 tiles.
struct TRP { const float* src[5]; __bf16* dst[5]; };
__global__ void __launch_bounds__(256) tr_cvt_all(TRP p) {
  __shared__ float tile[64][65];
  const int id = blockIdx.x;
  const int which = id >> 8;
  const int local = id & 255;
  const int bx = local & 15, by = local >> 4;
  const float* src = p.src[which];
  __bf16* dst = p.dst[which];
  int tx = threadIdx.x & 63, ty = threadIdx.x >> 6;
#pragma unroll
  for (int r = ty; r < 64; r += 4)
    tile[r][tx] = src[(long)(by * 64 + r) * 1024 + bx * 64 + tx];
  __syncthreads();
#pragma unroll
  for (int r = ty; r < 64; r += 4)
    dst[(long)(bx * 64 + r) * 1024 + by * 64 + tx] = (__bf16)tile[tx][r];
}

// -------- fused scores + rel-shift + softmax + PV: 4-wave blocks -----------
// 32 q-rows/block, 8 j-passes of width 256. Strips [32][QSTR3] f16 (qk, x)
// + xB[1024] f16. Per pass: qk+x MFMA + boundary copy + j==i+1 pre-zero ->
// barrier A -> packed-f16 exp2 in place -> barrier B -> PV -> barrier C.
#define QW 256
#define QSTR3 264                         // row stride f16 (256+8)
#define SM_ONE (32 * QSTR3 * 2)           // 16896 B per strip
#define FUSED_SMEM (2 * SM_ONE + 2048)    // 35840 B -> 4 blocks/CU

__global__ void __launch_bounds__(256, 4) fused_k(const __bf16* __restrict__ qb,
                                                  const __bf16* __restrict__ qrr,
                                                  const __bf16* __restrict__ kb,
                                                  const _Float16* __restrict__ vt,
                                                  const __bf16* __restrict__ rb,
                                                  const float* __restrict__ cb,
                                                  __bf16* __restrict__ attnb) {
  extern __shared__ char smem[];
  _Float16* qkS = (_Float16*)smem;              // [32][QSTR3]
  _Float16* xS  = (_Float16*)(smem + SM_ONE);   // [32][QSTR3]
  _Float16* xB  = (_Float16*)(smem + 2 * SM_ONE);  // [1024] boundary row
  __shared__ float sInv[32];

  const int t = threadIdx.x;
  const int w = t >> 6, lane = t & 63, lr = lane & 15, lq = lane >> 4;
  // XCD swizzle: all 64 tiles of a (b,h) on one XCD.
  const int obid = blockIdx.x;
  const int bid = ((obid & 7) << 8) | (obid >> 3);
  const int z  = bid >> 6;
  const int i0 = (bid & 63) << 5;
  const int b = z >> 4, h = z & 15;
  const bool early = (i0 <= 1023);
  const int astart = early ? i0 + 1 : i0;   // 32 MFMA x-rows [astart, astart+32)
  const int grow = early ? 0 : 31;          // boundary strip row
  const int c0   = early ? 0 : i0 + 33;     // boundary col range start

  // B-frags: q rows i0+rg*16+lr, qrr rows astart+rg*16+lr
  bf16x8 fq[2][2], fr[2][2];
#pragma unroll
  for (int rg2 = 0; rg2 < 2; rg2++) {
    const __bf16* qp = qb + (((long)z * 2048 + i0 + rg2 * 16 + lr) << 6) + lq * 8;
    fq[rg2][0] = *(const bf16x8*)qp; fq[rg2][1] = *(const bf16x8*)(qp + 32);
    const __bf16* rp = qrr + (((long)z * 2048 + astart + rg2 * 16 + lr) << 6) + lq * 8;
    fr[rg2][0] = *(const bf16x8*)rp; fr[rg2][1] = *(const bf16x8*)(rp + 32);
  }

  const __bf16* kbz = kb + (((long)z * 2048) << 6);
  const __bf16* rbh = rb + (((long)h * 2048) << 6);
  const float* cbz = cb + (long)z * 2048;
  const _Float16* vtz = vt + (((long)z) << 6) * 2048;

  // ---- boundary row, once per block, coalesced: 8 lanes per column --------
  {
    const int ga    = early ? i0 : i0 + 32;
    const int m0g   = early ? (2047 - i0) : 0;
    int ncols = early ? (i0 + 1) : (2015 - i0);
    if (ncols < 0) ncols = 0;
    const int dl = (t & 7) << 3;          // 8 d's per lane
    bf16x8 qv = *(const bf16x8*)(qrr + (((long)z * 2048 + ga) << 6) + dl);
    for (int c = t >> 3; c < ncols; c += 32) {
      bf16x8 rv = *(const bf16x8*)(rbh + ((long)(m0g + c) << 6) + dl);
      float s = 0.f;
#pragma unroll
      for (int e = 0; e < 8; e++) s += (float)qv[e] * (float)rv[e];
      s += __shfl_xor(s, 1, 64);
      s += __shfl_xor(s, 2, 64);
      s += __shfl_xor(s, 4, 64);
      if ((t & 7) == 0) xB[c] = (_Float16)(s * SCL);
    }
  }
  __syncthreads();   // xB visible to all waves

  const int erow = w * 8 + (lane >> 3);     // exp row for this lane
  const int ecol = (lane & 7) * 16;         // exp col base within half-pass
  const int rg = w >> 1, sl = w & 1;        // PV role: row-group, k-slice

  floatx4 oacc[4];
#pragma unroll
  for (int s = 0; s < 4; s++) oacc[s] = floatx4{0.f, 0.f, 0.f, 0.f};
  float psum = 0.f;

  for (int kp = 0; kp < 8; kp++) {
    const int J0 = kp << 8;

    // qk MFMA (+cb fold): 16 j-tiles, wave does 4. D: row=key-local, col=q-row.
#pragma unroll
    for (int s = 0; s < 4; s++) {
      const int jt = ((w << 2) + s) << 4;     // 0..240
      const __bf16* ap = kbz + ((long)(J0 + jt + lr) << 6) + lq * 8;
      bf16x8 a0 = *(const bf16x8*)ap, a1 = *(const bf16x8*)(ap + 32);
      floatx4 cbv = *(const floatx4*)(cbz + J0 + jt + lq * 4);
      floatx4 c0v{0.f, 0.f, 0.f, 0.f}, c1v{0.f, 0.f, 0.f, 0.f};
      c0v = __builtin_amdgcn_mfma_f32_16x16x32_bf16(a0, fq[0][0], c0v, 0, 0, 0);
      c0v = __builtin_amdgcn_mfma_f32_16x16x32_bf16(a1, fq[0][1], c0v, 0, 0, 0);
      c1v = __builtin_amdgcn_mfma_f32_16x16x32_bf16(a0, fq[1][0], c1v, 0, 0, 0);
      c1v = __builtin_amdgcn_mfma_f32_16x16x32_bf16(a1, fq[1][1], c1v, 0, 0, 0);
      f16x4 s0v, s1v;
#pragma unroll
      for (int g = 0; g < 4; g++) {
        s0v[g] = (_Float16)(c0v[g] * SCL + cbv[g]);
        s1v[g] = (_Float16)(c1v[g] * SCL + cbv[g]);
      }
      *(f16x4*)&qkS[lr * QSTR3 + jt + lq * 4] = s0v;
      *(f16x4*)&qkS[(16 + lr) * QSTR3 + jt + lq * 4] = s1v;
    }

    // x MFMA: m-window = 287 consecutive values -> <=19 tiles over 4 waves;
    // wave-uniform predicate. Scatter with shift pre-applied.
    const int mb = ((J0 - astart - 32) & 2047) & ~15;
#pragma unroll
    for (int s = 0; s < 5; s++) {
      const int mt = w + (s << 2);
      if (mt < 19) {
        const int m0 = (mb + (mt << 4)) & 2047;
        const __bf16* rp2 = rbh + ((long)(m0 + lr) << 6) + lq * 8;
        bf16x8 r0 = *(const bf16x8*)rp2, r1 = *(const bf16x8*)(rp2 + 32);
        floatx4 x0{0.f, 0.f, 0.f, 0.f}, x1{0.f, 0.f, 0.f, 0.f};
        x0 = __builtin_amdgcn_mfma_f32_16x16x32_bf16(r0, fr[0][0], x0, 0, 0, 0);
        x0 = __builtin_amdgcn_mfma_f32_16x16x32_bf16(r1, fr[0][1], x0, 0, 0, 0);
        x1 = __builtin_amdgcn_mfma_f32_16x16x32_bf16(r0, fr[1][0], x1, 0, 0, 0);
        x1 = __builtin_amdgcn_mfma_f32_16x16x32_bf16(r1, fr[1][1], x1, 0, 0, 0);
#pragma unroll
        for (int rg2 = 0; rg2 < 2; rg2++) {
          const int a = astart + (rg2 << 4) + lr;
          const floatx4 ax = rg2 ? x1 : x0;
#pragma unroll
          for (int g = 0; g < 4; g++) {
            const int m = m0 + (lq << 2) + g;
            const int sum = m + a + 1;
            const int j = sum & 2047;
            const int ri = (sum >= 2048) ? (a - i0) : (a - i0 - 1);
            const int jl = j - J0;
            if ((unsigned)ri < 32u && (unsigned)jl < (unsigned)QW)
              xS[ri * QSTR3 + jl] = (_Float16)(ax[g] * SCL);
          }
        }
      }
    }

    // boundary slice: each thread copies 1 col of this pass from xB
    {
      const int j = J0 + t;
      const bool act = early ? (j <= i0) : (j >= c0);
      if (act) xS[grow * QSTR3 + t] = xB[j - c0];
    }
    // pre-zero the j==i+1 hole of each row (collision-free: no scatter or
    // boundary-copy write ever targets (row i, col i+1))
    if (t < 32) {
      const int jl = i0 + t + 1 - J0;
      if ((unsigned)jl < (unsigned)QW) xS[t * QSTR3 + jl] = (_Float16)0.f;
    }
    __syncthreads();   // A: strips complete

    // packed-f16 exp2 in place: row erow, 2 x 16 cols. No selects, no index
    // math: score+x via v_pk_add_f16, exp2 via v_exp_f16, psum via fdot2.
    {
      _Float16* qrow = qkS + erow * QSTR3;
      const _Float16* xrow = xS + erow * QSTR3;
      const f16x2 one2 = {(_Float16)1.f, (_Float16)1.f};
#pragma unroll
      for (int ii = 0; ii < 2; ii++) {
        const int cbase = ii * 128 + ecol;
        f16x8 h0 = *(const f16x8*)(qrow + cbase), h1 = *(const f16x8*)(qrow + cbase + 8);
        f16x8 v0 = *(const f16x8*)(xrow + cbase), v1 = *(const f16x8*)(xrow + cbase + 8);
        f16x8 s0 = h0 + v0, s1 = h1 + v1;
        f16x8 p0, p1;
#pragma unroll
        for (int e2 = 0; e2 < 4; e2++) {
          __half2 a2, b2;
          __builtin_memcpy(&a2, (const char*)&s0 + e2 * 4, 4);
          a2 = h2exp2(a2);
          __builtin_memcpy((char*)&p0 + e2 * 4, &a2, 4);
          f16x2 af2; __builtin_memcpy(&af2, &a2, 4);
          psum = __builtin_amdgcn_fdot2(af2, one2, psum, false);
          __builtin_memcpy(&b2, (const char*)&s1 + e2 * 4, 4);
          b2 = h2exp2(b2);
          __builtin_memcpy((char*)&p1 + e2 * 4, &b2, 4);
          f16x2 bf2; __builtin_memcpy(&bf2, &b2, 4);
          psum = __builtin_amdgcn_fdot2(bf2, one2, psum, false);
        }
        *(f16x8*)(qrow + cbase) = p0;
        *(f16x8*)(qrow + cbase + 8) = p1;
      }
    }
    __syncthreads();   // B: p~ complete

    // PV: wave (rg, sl) contracts keys [J0+sl*128, +128) for rows rg*16..+16
#pragma unroll
    for (int ch = 0; ch < 4; ch++) {
      const int kk = sl * 128 + ch * 32;
      f16x8 af = *(const f16x8*)(qkS + (rg * 16 + lr) * QSTR3 + kk + lq * 8);
#pragma unroll
      for (int sub = 0; sub < 4; sub++) {
        f16x8 bfv = *(const f16x8*)(vtz + (long)(sub * 16 + lr) * 2048 + J0 + kk + lq * 8);
        oacc[sub] = __builtin_amdgcn_mfma_f32_16x16x32_f16(af, bfv, oacc[sub], 0, 0, 0);
      }
    }
    __syncthreads();   // C: strip reads done before next pass overwrites
  }

  // fp32 partials overlay the strips (dead after barrier C of last pass)
  {
    float* sPart = (float*)smem;   // [2*rg+sl][16][64]
#pragma unroll
    for (int sub = 0; sub < 4; sub++)
#pragma unroll
      for (int g = 0; g < 4; g++)
        sPart[((rg << 1) + sl) * 1024 + ((lq << 2) + g) * 64 + sub * 16 + lr] = oacc[sub][g];
  }
  // row sums: reduce 8 col-lanes of each row
#pragma unroll
  for (int o = 1; o < 8; o <<= 1) psum += __shfl_xor(psum, o, 64);
  if ((lane & 7) == 0) sInv[erow] = 1.0f / psum;
  __syncthreads();   // D: partials + sInv complete

  // final: 256 threads x 8 outputs (32 rows x 64 d)
  {
    const float* sPart = (const float*)smem;
    const int r = t >> 3, d0 = (t & 7) << 3;
    const int rg2 = r >> 4, rl = r & 15;
    const float inv = sInv[r];
    bf16x8 ov;
#pragma unroll
    for (int e = 0; e < 8; e++) {
      float acc = sPart[(rg2 << 1) * 1024 + rl * 64 + d0 + e] +
                  sPart[((rg2 << 1) + 1) * 1024 + rl * 64 + d0 + e];
      ov[e] = (__bf16)(acc * inv);
    }
    *(bf16x8*)&attnb[((long)b * 2048 + i0 + r) * 1024 + h * 64 + d0] = ov;
  }
}

extern "C" void kernel_launch(void* const* d_in, const int* in_sizes, int n_in,
                              void* d_out, int out_size, void* d_ws, size_t ws_size,
                              hipStream_t stream) {
  (void)in_sizes; (void)n_in; (void)out_size; (void)ws_size;
  const float* inputs_kv = (const float*)d_in[0];
  const float* inputs_q  = (const float*)d_in[1];
  const float* pos_embed = (const float*)d_in[2];
  const float* Wq_w = (const float*)d_in[3];
  const float* Wq_b = (const float*)d_in[4];
  const float* Wk_w = (const float*)d_in[5];
  const float* Wk_b = (const float*)d_in[6];
  const float* Wv_w = (const float*)d_in[7];
  const float* Wv_b = (const float*)d_in[8];
  const float* Wr_w = (const float*)d_in[9];
  const float* rwb  = (const float*)d_in[10];
  const float* rrb  = (const float*)d_in[11];
  const float* Wo_w = (const float*)d_in[12];
  const float* Wo_b = (const float*)d_in[13];

  char* ws = (char*)d_ws;
  const long MB = 1 << 20;
  __bf16* Wtq = (__bf16*)(ws + 0 * MB);
  __bf16* Wtk = (__bf16*)(ws + 2 * MB);
  __bf16* Wtv = (__bf16*)(ws + 4 * MB);
  __bf16* Wtr = (__bf16*)(ws + 6 * MB);
  __bf16* Wto = (__bf16*)(ws + 8 * MB);
  __bf16* qb  = (__bf16*)(ws + 10 * MB);
  __bf16* qrr = (__bf16*)(ws + 18 * MB);
  __bf16* kb  = (__bf16*)(ws + 26 * MB);
  _Float16* vt = (_Float16*)(ws + 34 * MB);
  __bf16* rb  = (__bf16*)(ws + 42 * MB);
  float*  cb  = (float*)(ws + 46 * MB);               // 256 KB
  __bf16* attnb = (__bf16*)(ws + 47 * MB);            // 8 MB bf16 attention out

  dim3 blk(256);

  TRP tp{};
  tp.src[0] = Wq_w; tp.dst[0] = Wtq;
  tp.src[1] = Wk_w; tp.dst[1] = Wtk;
  tp.src[2] = Wv_w; tp.dst[2] = Wtv;
  tp.src[3] = Wr_w; tp.dst[3] = Wtr;
  tp.src[4] = Wo_w; tp.dst[4] = Wto;
  tr_cvt_all<<<dim3(1280), blk, 0, stream>>>(tp);

  QPAll q{};
  q.qin = inputs_q; q.kvin = inputs_kv; q.pos = pos_embed;
  q.Wtq = Wtq; q.Wtk = Wtk; q.Wtv = Wtv; q.Wtr = Wtr;
  q.bq = Wq_b; q.bk = Wk_b; q.bv = Wv_b; q.rrb = rrb;
  q.qb = qb; q.qrr = qrr; q.kb = kb; q.rb = rb; q.vt = vt;
  qkvr_k<<<dim3(896), blk, 0, stream>>>(q);

  cb_k<<<dim3(256), blk, 0, stream>>>(kb, rwb, cb);

  fused_k<<<dim3(2048), dim3(256), FUSED_SMEM, stream>>>(qb, qrr, kb, vt, rb, cb, attnb);

  // Output projection: d_out = attn(bf16) @ Wo + bo
  GP o{};
  o.A = attnb; o.B = Wto; o.lda = 1024; o.ldb = 1024; o.K = 1024;
  o.bias = Wo_b; o.outF = (float*)d_out;
  gemm_o<<<dim3(8, 64), blk, 0, stream>>>(o);
}